// Round 3
// baseline (23807.251 us; speedup 1.0000x reference)
//
#include <hip/hip_runtime.h>
#include <hip/hip_fp16.h>
#include <math.h>

// Problem dims (fixed)
#define T_SEQ 4096
#define DIN   64
#define DM    1024
#define G4    4096              // 4*DM gate rows
#define LSTRIDE_W ((size_t)G4 * DM)   // per-layer Wih/Whh stride
#define LSTRIDE_B ((size_t)G4)        // per-layer bias stride

#define SENT 0x7FC0DEADu        // qNaN payload: unreachable as an h0 value

typedef unsigned long long u64;
typedef unsigned int u32;

__device__ __forceinline__ float sigmoidf_(float x) {
    return 1.0f / (1.0f + __expf(-x));
}
__device__ __forceinline__ float tanhf_(float x) {
    float ax = fabsf(x);
    float e  = __expf(-2.0f * ax);
    float t  = (1.0f - e) / (1.0f + e);
    return copysignf(t, x);
}
__device__ __forceinline__ float lrelu_(float x) {
    return x > 0.0f ? x : 0.01f * x;
}

// pack two fp32 -> one u32 of two f16 (v_cvt_pkrtz_f16_f32)
__device__ __forceinline__ u32 pk2_(float x, float y) {
    typedef __fp16 hv2 __attribute__((ext_vector_type(2)));
    union { hv2 h; u32 u; } c;
    c.h = __builtin_amdgcn_cvt_pkrtz(x, y);
    return c.u;
}
// fused f16-pair dot-accumulate: acc += a.x*b.x + a.y*b.y
#if __has_builtin(__builtin_amdgcn_fdot2)
__device__ __forceinline__ float d2a_(u32 a, u32 b, float acc) {
    typedef __fp16 hv2 __attribute__((ext_vector_type(2)));
    union { u32 u; hv2 h; } ua, ub;
    ua.u = a; ub.u = b;
    return __builtin_amdgcn_fdot2(ua.h, ub.h, acc, false);
}
#else
__device__ __forceinline__ float d2a_(u32 a, u32 b, float acc) {
    union { u32 u; __half2 h; } ua, ub;
    ua.u = a; ub.u = b;
    float2 fa = __half22float2(ua.h);
    float2 fb = __half22float2(ub.h);
    return acc + fa.x * fb.x + fa.y * fb.y;
}
#endif
__device__ __forceinline__ float dot8a_(uint4 q, uint4 h, float acc) {
    acc = d2a_(q.x, h.x, acc);
    acc = d2a_(q.y, h.y, acc);
    acc = d2a_(q.z, h.z, acc);
    acc = d2a_(q.w, h.w, acc);
    return acc;
}

// ---------------------------------------------------------------------------
// K1: x[t,d] = leaky_relu(sum_k inp[t,k]*W1[d,k] + b1[d]);  grid=4096, block=256
// ---------------------------------------------------------------------------
__global__ __launch_bounds__(256) void k_input(const float* __restrict__ inp,
                                               const float* __restrict__ W1,
                                               const float* __restrict__ b1,
                                               float* __restrict__ x) {
    __shared__ float s_in[DIN];
    const int t   = blockIdx.x;
    const int tid = threadIdx.x;
    if (tid < DIN) s_in[tid] = inp[(size_t)t * DIN + tid];
    __syncthreads();
#pragma unroll
    for (int q = 0; q < 4; q++) {
        const int d = tid + q * 256;
        const float4* wr = (const float4*)(W1 + (size_t)d * DIN);
        float acc = 0.0f;
#pragma unroll
        for (int e = 0; e < 16; e++) {
            float4 w = wr[e];
            acc += w.x * s_in[e * 4 + 0] + w.y * s_in[e * 4 + 1] +
                   w.z * s_in[e * 4 + 2] + w.w * s_in[e * 4 + 3];
        }
        acc += b1[d];
        x[(size_t)t * DM + d] = lrelu_(acc);
    }
}

// ---------------------------------------------------------------------------
// K2: xg[m,n] = sum_k x[m,k]*Wih0[n,k] + (bih0[n]+bhh0[n])
// 128x128 tile, BK=16, 256 threads, 8x8 per thread.
// ---------------------------------------------------------------------------
__global__ __launch_bounds__(256) void k_gemm(const float* __restrict__ A,
                                              const float* __restrict__ B,
                                              const float* __restrict__ bih,
                                              const float* __restrict__ bhh,
                                              float* __restrict__ C) {
    const int K = DM;
    __shared__ float As[16][132];
    __shared__ float Bs[16][132];
    const int tid = threadIdx.x;
    const int m0 = blockIdx.y * 128, n0 = blockIdx.x * 128;
    const int tx = tid & 15, ty = tid >> 4;
    const int lr = tid >> 1;
    const int lc = (tid & 1) * 8;

    float acc[8][8] = {};
    const float4* ag = (const float4*)(A + (size_t)(m0 + lr) * K + lc);
    const float4* bg = (const float4*)(B + (size_t)(n0 + lr) * K + lc);

    for (int k0 = 0; k0 < K; k0 += 16) {
        float4 a0 = ag[0], a1 = ag[1];
        float4 b0 = bg[0], b1v = bg[1];
        ag += 4; bg += 4;
        __syncthreads();
        As[lc + 0][lr] = a0.x; As[lc + 1][lr] = a0.y; As[lc + 2][lr] = a0.z; As[lc + 3][lr] = a0.w;
        As[lc + 4][lr] = a1.x; As[lc + 5][lr] = a1.y; As[lc + 6][lr] = a1.z; As[lc + 7][lr] = a1.w;
        Bs[lc + 0][lr] = b0.x; Bs[lc + 1][lr] = b0.y; Bs[lc + 2][lr] = b0.z; Bs[lc + 3][lr] = b0.w;
        Bs[lc + 4][lr] = b1v.x; Bs[lc + 5][lr] = b1v.y; Bs[lc + 6][lr] = b1v.z; Bs[lc + 7][lr] = b1v.w;
        __syncthreads();
#pragma unroll
        for (int k = 0; k < 16; k++) {
            float a[8], b[8];
            *(float4*)&a[0] = *(const float4*)&As[k][ty * 8 + 0];
            *(float4*)&a[4] = *(const float4*)&As[k][ty * 8 + 4];
            *(float4*)&b[0] = *(const float4*)&Bs[k][tx * 8 + 0];
            *(float4*)&b[4] = *(const float4*)&Bs[k][tx * 8 + 4];
#pragma unroll
            for (int i = 0; i < 8; i++)
#pragma unroll
                for (int j = 0; j < 8; j++)
                    acc[i][j] += a[i] * b[j];
        }
    }
    float bj[8];
#pragma unroll
    for (int j = 0; j < 8; j++) {
        int n = n0 + tx * 8 + j;
        bj[j] = bih[n] + bhh[n];
    }
#pragma unroll
    for (int i = 0; i < 8; i++) {
        float4 v0, v1;
        v0.x = acc[i][0] + bj[0]; v0.y = acc[i][1] + bj[1];
        v0.z = acc[i][2] + bj[2]; v0.w = acc[i][3] + bj[3];
        v1.x = acc[i][4] + bj[4]; v1.y = acc[i][5] + bj[5];
        v1.z = acc[i][6] + bj[6]; v1.w = acc[i][7] + bj[7];
        float* cp = C + (size_t)(m0 + ty * 8 + i) * G4 + n0 + tx * 8;
        *(float4*)(cp + 0) = v0;
        *(float4*)(cp + 4) = v1;
    }
}

// ---------------------------------------------------------------------------
// K2b: sentinel-clear the h0 history region (reuses the dead x buffer).
// 4096 blocks x 256 threads x 16B = 16 MB.
// ---------------------------------------------------------------------------
__global__ __launch_bounds__(256) void k_clear(u32* __restrict__ p) {
    uint4 v; v.x = SENT; v.y = SENT; v.z = SENT; v.w = SENT;
    ((uint4*)p)[(size_t)blockIdx.x * 256 + threadIdx.x] = v;
}

// ---------------------------------------------------------------------------
// K3: R13 = DECOUPLED layer scans. blockIdx<256: L0 WGs; >=256: L1 WGs.
//
// R10 paid 2 serialized MALL round-trips + 2 barriers per round (h0 then h1
// in lockstep, ~6300cy). R11/R12 proved poll-placement tweaks can't remove
// them. R13 removes the lockstep: layer 1 only needs the h0 *stream*, so L0
// publishes h0(t) once into a sentinel-valued u32 history (h0hist, reusing
// dead x memory, cleared by k_clear) and runs free. L1 WGs consume the
// history at their own pace and keep their private h1 ring (R10's proven
// tagged parity slots). Each loop: ONE exchange RT + ONE barrier per round
// (parity double-buffer makes a single __syncthreads sufficient: staging of
// round t+2 into buffer [par] happens after B1(t+1), which orders it after
// all dot-reads of round t).
//
// All weights live in VGPRs (L0: 32 regs Whh0; L1: 64 regs Wih1+Whh1) ->
// LDS is just 9 KB of staging -> 2 WGs/CU (512 blocks all co-resident:
// VGPR<=256 via launch_bounds(256,2), 8 waves/CU of 32).
//
// Poll discipline (R9/R11/R12 lessons): demand polls only, unpaced on the
// critical rings (R10-style); ONLY the L1->h0hist catch-up retry is paced
// with s_sleep (it fires only when L0 is behind, exactly when backoff is
// wanted; in steady state L0 leads and the first read hits).
// ---------------------------------------------------------------------------
__global__ __launch_bounds__(256, 2) void k_scan2(
        const float* __restrict__ xg,     // T x 4096 layer-0 preacts
        const float* __restrict__ Wih1,
        const float* __restrict__ Whh0,
        const float* __restrict__ Whh1,
        const float* __restrict__ bih1,
        const float* __restrict__ bhh1,
        u32* h0hist,                      // [T][1024] h0 stream (sentinel-init)
        u64* sl1,                         // [2][1024] tagged h1 slots
        float* __restrict__ out) {
    const int tid  = threadIdx.x;
    const bool isL0 = (blockIdx.x < 256);
    const int w    = isL0 ? blockIdx.x : (blockIdx.x - 256);
    const int wv   = tid >> 6;            // wave 0..3 == state index s
    const int ln   = tid & 63;            // lane
    const int rs   = tid >> 4;            // row slot 0..15 (s_i = rs>>2 == wv)
    const int ck   = tid & 15;            // k-chunk of 64
    const int g_i  = rs & 3;              // gate
    const int r    = g_i * DM + w * 4 + wv;   // global gate row

    __shared__ uint4 hstA[2][16][9];      // h0 staged (f16), parity dbuf
    __shared__ uint4 hstB[2][16][9];      // h1 staged (f16), parity dbuf (L1)

    const int stc = tid >> 4;             // stage chunk for h[tid*4..+4)
    const int sto = tid & 15;             // u64 index within chunk row

    if (isL0) {
        // ---------------- Layer-0 producer loop ----------------
        uint4 wr0[8];                     // Whh0 row r as f16 pairs (32 VGPR)
        {
            const float4* gw = (const float4*)(Whh0 + (size_t)r * DM + ck * 64);
#pragma unroll
            for (int e = 0; e < 8; e++) {
                float4 a = gw[2 * e], b = gw[2 * e + 1];
                uint4 q;
                q.x = pk2_(a.x, a.y); q.y = pk2_(a.z, a.w);
                q.z = pk2_(b.x, b.y); q.w = pk2_(b.z, b.w);
                wr0[e] = q;
            }
        }
        float c0 = 0.f, h0v = 0.f;
        float xgv = (ck == 0) ? xg[r] : 0.f;

        for (int t = 0; t < T_SEQ; t++) {
            const int par = t & 1;
            // stage h0(t-1): poll history row t-1 (sentinel protocol).
            if (t == 0) {
                ((u64*)&hstA[0][stc][0])[sto] = 0ull;
            } else {
                const u32* hp = h0hist + (size_t)(t - 1) * DM + tid * 4;
                u32 v0, v1, v2, v3;
                for (;;) {
                    v0 = __hip_atomic_load(hp + 0, __ATOMIC_RELAXED, __HIP_MEMORY_SCOPE_AGENT);
                    v1 = __hip_atomic_load(hp + 1, __ATOMIC_RELAXED, __HIP_MEMORY_SCOPE_AGENT);
                    v2 = __hip_atomic_load(hp + 2, __ATOMIC_RELAXED, __HIP_MEMORY_SCOPE_AGENT);
                    v3 = __hip_atomic_load(hp + 3, __ATOMIC_RELAXED, __HIP_MEMORY_SCOPE_AGENT);
                    if ((v0 != SENT) & (v1 != SENT) & (v2 != SENT) & (v3 != SENT)) break;
                }
                u32 q0 = pk2_(__uint_as_float(v0), __uint_as_float(v1));
                u32 q1 = pk2_(__uint_as_float(v2), __uint_as_float(v3));
                ((u64*)&hstA[par][stc][0])[sto] = ((u64)q1 << 32) | q0;
            }
            __syncthreads();              // the ONLY barrier per round

            // dot0: Whh0 row r · h0(t-1), weights in VGPRs
            float acc = 0.f;
#pragma unroll
            for (int e = 0; e < 8; e++)
                acc = dot8a_(wr0[e], hstA[par][ck][e], acc);
#pragma unroll
            for (int m = 1; m <= 8; m <<= 1) acc += __shfl_xor(acc, m, 64);
            if (ck == 0) acc += xgv;      // lanes 0,16,32,48 hold gate preacts

            float pi = __shfl(acc, 0, 64);
            float pf = __shfl(acc, 16, 64);
            float pg = __shfl(acc, 32, 64);
            float po = __shfl(acc, 48, 64);
            if (ln == 0) {
                c0 = sigmoidf_(pf) * c0 + sigmoidf_(pi) * tanhf_(pg);
                h0v = sigmoidf_(po) * tanhf_(c0);
                __hip_atomic_store(h0hist + (size_t)t * DM + w * 4 + wv,
                                   __float_as_uint(h0v),
                                   __ATOMIC_RELAXED, __HIP_MEMORY_SCOPE_AGENT);
            }
            // xg prefetch for t+1 (off the critical chain)
            float xgn = 0.f;
            if (ck == 0 && t + 1 < T_SEQ) xgn = xg[(size_t)(t + 1) * G4 + r];
            xgv = xgn;
        }
        // L0 WGs exit; h0hist persists for L1 consumers.
    } else {
        // ---------------- Layer-1 consumer loop ----------------
        uint4 wi1[8], wh1[8];             // Wih1/Whh1 rows (64 VGPR)
        {
            const float4* ga = (const float4*)(Wih1 + (size_t)r * DM + ck * 64);
            const float4* gb = (const float4*)(Whh1 + (size_t)r * DM + ck * 64);
#pragma unroll
            for (int e = 0; e < 8; e++) {
                float4 a = ga[2 * e], b = ga[2 * e + 1];
                uint4 q;
                q.x = pk2_(a.x, a.y); q.y = pk2_(a.z, a.w);
                q.z = pk2_(b.x, b.y); q.w = pk2_(b.z, b.w);
                wi1[e] = q;
                a = gb[2 * e]; b = gb[2 * e + 1];
                q.x = pk2_(a.x, a.y); q.y = pk2_(a.z, a.w);
                q.z = pk2_(b.x, b.y); q.w = pk2_(b.z, b.w);
                wh1[e] = q;
            }
        }
        float b1s[4] = {0.f, 0.f, 0.f, 0.f};
        if (ln == 0) {
#pragma unroll
            for (int gg = 0; gg < 4; gg++)
                b1s[gg] = bih1[gg * DM + w * 4 + wv] + bhh1[gg * DM + w * 4 + wv];
        }
        float c1 = 0.f, h1v = 0.f;

        for (int t = 0; t < T_SEQ; t++) {
            const int par = t & 1;

            // (a) stage h0(t) from history. Steady state: L0 leads -> first
            //     read hits. Catch-up retries are s_sleep-paced (backoff only
            //     when the producer is behind; never on the h1 ring).
            {
                const u32* hp = h0hist + (size_t)t * DM + tid * 4;
                u32 v0, v1, v2, v3;
                v0 = __hip_atomic_load(hp + 0, __ATOMIC_RELAXED, __HIP_MEMORY_SCOPE_AGENT);
                v1 = __hip_atomic_load(hp + 1, __ATOMIC_RELAXED, __HIP_MEMORY_SCOPE_AGENT);
                v2 = __hip_atomic_load(hp + 2, __ATOMIC_RELAXED, __HIP_MEMORY_SCOPE_AGENT);
                v3 = __hip_atomic_load(hp + 3, __ATOMIC_RELAXED, __HIP_MEMORY_SCOPE_AGENT);
                while ((v0 == SENT) | (v1 == SENT) | (v2 == SENT) | (v3 == SENT)) {
                    __builtin_amdgcn_s_sleep(2);
                    v0 = __hip_atomic_load(hp + 0, __ATOMIC_RELAXED, __HIP_MEMORY_SCOPE_AGENT);
                    v1 = __hip_atomic_load(hp + 1, __ATOMIC_RELAXED, __HIP_MEMORY_SCOPE_AGENT);
                    v2 = __hip_atomic_load(hp + 2, __ATOMIC_RELAXED, __HIP_MEMORY_SCOPE_AGENT);
                    v3 = __hip_atomic_load(hp + 3, __ATOMIC_RELAXED, __HIP_MEMORY_SCOPE_AGENT);
                }
                u32 q0 = pk2_(__uint_as_float(v0), __uint_as_float(v1));
                u32 q1 = pk2_(__uint_as_float(v2), __uint_as_float(v3));
                ((u64*)&hstA[par][stc][0])[sto] = ((u64)q1 << 32) | q0;
            }

            // (b) stage h1(t-1) from the tagged ring (unpaced demand poll)
            if (t == 0) {
                ((u64*)&hstB[0][stc][0])[sto] = 0ull;
            } else {
                const u64* p1 = sl1 + (size_t)par * 1024 + tid * 4;
                const u32 want = (u32)t;
                u64 d0, d1, d2, d3;
                for (;;) {
                    d0 = __hip_atomic_load(p1 + 0, __ATOMIC_RELAXED, __HIP_MEMORY_SCOPE_AGENT);
                    d1 = __hip_atomic_load(p1 + 1, __ATOMIC_RELAXED, __HIP_MEMORY_SCOPE_AGENT);
                    d2 = __hip_atomic_load(p1 + 2, __ATOMIC_RELAXED, __HIP_MEMORY_SCOPE_AGENT);
                    d3 = __hip_atomic_load(p1 + 3, __ATOMIC_RELAXED, __HIP_MEMORY_SCOPE_AGENT);
                    bool ok = ((u32)(d0 >> 32) == want) & ((u32)(d1 >> 32) == want) &
                              ((u32)(d2 >> 32) == want) & ((u32)(d3 >> 32) == want);
                    if (ok) break;
                }
                u32 q0 = pk2_(__uint_as_float((u32)d0), __uint_as_float((u32)d1));
                u32 q1 = pk2_(__uint_as_float((u32)d2), __uint_as_float((u32)d3));
                ((u64*)&hstB[par][stc][0])[sto] = ((u64)q1 << 32) | q0;
            }
            __syncthreads();              // the ONLY barrier per round

            // dot1: Wih1·h0(t); dot2: Whh1·h1(t-1) — both weights in VGPRs
            float a1 = 0.f, a2 = 0.f;
#pragma unroll
            for (int e = 0; e < 8; e++) {
                a1 = dot8a_(wi1[e], hstA[par][ck][e], a1);
                a2 = dot8a_(wh1[e], hstB[par][ck][e], a2);
            }
#pragma unroll
            for (int m = 1; m <= 8; m <<= 1) {
                a1 += __shfl_xor(a1, m, 64);
                a2 += __shfl_xor(a2, m, 64);
            }
            float pi = __shfl(a1, 0, 64)  + __shfl(a2, 0, 64);
            float pf = __shfl(a1, 16, 64) + __shfl(a2, 16, 64);
            float pg = __shfl(a1, 32, 64) + __shfl(a2, 32, 64);
            float po = __shfl(a1, 48, 64) + __shfl(a2, 48, 64);
            if (ln == 0) {
                pi += b1s[0]; pf += b1s[1]; pg += b1s[2]; po += b1s[3];
                c1 = sigmoidf_(pf) * c1 + sigmoidf_(pi) * tanhf_(pg);
                h1v = sigmoidf_(po) * tanhf_(c1);
                u64 v = ((u64)(u32)(t + 1) << 32) | (u64)__float_as_uint(h1v);
                __hip_atomic_store(sl1 + (size_t)((t + 1) & 1) * 1024 + w * 4 + wv,
                                   v, __ATOMIC_RELAXED, __HIP_MEMORY_SCOPE_AGENT);
            }
            // Hazards (single barrier): hstA/hstB[par] written pre-B1(t),
            // read post-B1(t); next write to same parity is pre-B1(t+2),
            // i.e. after B1(t+1), which orders it after all round-t reads.
            // Ring tags: stale cross-run values are 4095/4096, never equal
            // to the small wanted tags before first overwrite -> no false
            // positives (same argument as R10).
        }
        if (ln == 0) out[w * 4 + wv] = lrelu_(h1v);   // h1[T-1]
    }
}

// ---------------------------------------------------------------------------
extern "C" void kernel_launch(void* const* d_in, const int* in_sizes, int n_in,
                              void* d_out, int out_size, void* d_ws, size_t ws_size,
                              hipStream_t stream) {
    const float* inp = (const float*)d_in[0];   // 4096 x 64
    const float* W1  = (const float*)d_in[1];   // 1024 x 64
    const float* b1  = (const float*)d_in[2];   // 1024
    const float* Wih = (const float*)d_in[3];   // 2 x 4096 x 1024
    const float* Whh = (const float*)d_in[4];   // 2 x 4096 x 1024
    const float* bih = (const float*)d_in[5];   // 2 x 4096
    const float* bhh = (const float*)d_in[6];   // 2 x 4096
    float* out = (float*)d_out;                 // 1024

    // workspace layout (same 80 MB footprint as R10):
    //   x: 4096*1024 f32 (K1 out, K2 in) -> REUSED as h0hist (16 MB) after K2
    //   xg: 4096*4096 f32
    //   sl1: 2*1024 u64
    float* x   = (float*)d_ws;
    float* xg  = x + (size_t)T_SEQ * DM;
    u64*   sl1 = (u64*)(xg + (size_t)T_SEQ * G4);
    u32*   h0hist = (u32*)x;
    (void)in_sizes; (void)n_in; (void)out_size; (void)ws_size;

    // Phase 1: input projection
    k_input<<<dim3(T_SEQ), dim3(256), 0, stream>>>(inp, W1, b1, x);

    // Phase 2: xg = x @ Wih0^T + (bih0+bhh0)
    k_gemm<<<dim3(32, 32), dim3(256), 0, stream>>>(x, Wih, bih, bhh, xg);

    // Phase 2b: x is now dead -> sentinel-clear it as the h0 history
    k_clear<<<dim3(4096), dim3(256), 0, stream>>>(h0hist);

    // Phase 3: decoupled layer scans (256 L0 WGs + 256 L1 WGs, 2/CU)
    k_scan2<<<dim3(512), dim3(256), 0, stream>>>(
        xg, Wih + LSTRIDE_W, Whh, Whh + LSTRIDE_W,
        bih + LSTRIDE_B, bhh + LSTRIDE_B, h0hist, sl1, out);
}

// Round 4
// 10130.070 us; speedup vs baseline: 2.3502x; 2.3502x over previous
//
#include <hip/hip_runtime.h>
#include <hip/hip_fp16.h>
#include <math.h>

// Problem dims (fixed)
#define T_SEQ 4096
#define DIN   64
#define DM    1024
#define G4    4096              // 4*DM gate rows
#define LSTRIDE_W ((size_t)G4 * DM)   // per-layer Wih/Whh stride
#define LSTRIDE_B ((size_t)G4)        // per-layer bias stride

#define SENT 0x7FC0DEADu        // qNaN payload: unreachable as an h0 value

// timed-wait quanta (s_sleep N ~= 64*N cycles)
#define S_RING  32              // ~2048 cy: zero-gap ring visibility wait
#define S_RETRY 4               // ~256 cy: paced retry
#define S_HIST  8               // ~512 cy: L1 catch-up on h0hist (L0 behind)

typedef unsigned long long u64;
typedef unsigned int u32;

// sleep + compiler memory fence (prevent hoisting the following atomic
// loads above the sleep)
#define PAUSE(n) do { __builtin_amdgcn_s_sleep(n); asm volatile("" ::: "memory"); } while (0)

__device__ __forceinline__ float sigmoidf_(float x) {
    return 1.0f / (1.0f + __expf(-x));
}
__device__ __forceinline__ float tanhf_(float x) {
    float ax = fabsf(x);
    float e  = __expf(-2.0f * ax);
    float t  = (1.0f - e) / (1.0f + e);
    return copysignf(t, x);
}
__device__ __forceinline__ float lrelu_(float x) {
    return x > 0.0f ? x : 0.01f * x;
}

// pack two fp32 -> one u32 of two f16 (v_cvt_pkrtz_f16_f32)
__device__ __forceinline__ u32 pk2_(float x, float y) {
    typedef __fp16 hv2 __attribute__((ext_vector_type(2)));
    union { hv2 h; u32 u; } c;
    c.h = __builtin_amdgcn_cvt_pkrtz(x, y);
    return c.u;
}
// fused f16-pair dot-accumulate: acc += a.x*b.x + a.y*b.y
#if __has_builtin(__builtin_amdgcn_fdot2)
__device__ __forceinline__ float d2a_(u32 a, u32 b, float acc) {
    typedef __fp16 hv2 __attribute__((ext_vector_type(2)));
    union { u32 u; hv2 h; } ua, ub;
    ua.u = a; ub.u = b;
    return __builtin_amdgcn_fdot2(ua.h, ub.h, acc, false);
}
#else
__device__ __forceinline__ float d2a_(u32 a, u32 b, float acc) {
    union { u32 u; __half2 h; } ua, ub;
    ua.u = a; ub.u = b;
    float2 fa = __half22float2(ua.h);
    float2 fb = __half22float2(ub.h);
    return acc + fa.x * fb.x + fa.y * fb.y;
}
#endif
__device__ __forceinline__ float dot8a_(uint4 q, uint4 h, float acc) {
    acc = d2a_(q.x, h.x, acc);
    acc = d2a_(q.y, h.y, acc);
    acc = d2a_(q.z, h.z, acc);
    acc = d2a_(q.w, h.w, acc);
    return acc;
}

// ---------------------------------------------------------------------------
// K1: x[t,d] = leaky_relu(sum_k inp[t,k]*W1[d,k] + b1[d]);  grid=4096, block=256
// ---------------------------------------------------------------------------
__global__ __launch_bounds__(256) void k_input(const float* __restrict__ inp,
                                               const float* __restrict__ W1,
                                               const float* __restrict__ b1,
                                               float* __restrict__ x) {
    __shared__ float s_in[DIN];
    const int t   = blockIdx.x;
    const int tid = threadIdx.x;
    if (tid < DIN) s_in[tid] = inp[(size_t)t * DIN + tid];
    __syncthreads();
#pragma unroll
    for (int q = 0; q < 4; q++) {
        const int d = tid + q * 256;
        const float4* wr = (const float4*)(W1 + (size_t)d * DIN);
        float acc = 0.0f;
#pragma unroll
        for (int e = 0; e < 16; e++) {
            float4 w = wr[e];
            acc += w.x * s_in[e * 4 + 0] + w.y * s_in[e * 4 + 1] +
                   w.z * s_in[e * 4 + 2] + w.w * s_in[e * 4 + 3];
        }
        acc += b1[d];
        x[(size_t)t * DM + d] = lrelu_(acc);
    }
}

// ---------------------------------------------------------------------------
// K2: xg[m,n] = sum_k x[m,k]*Wih0[n,k] + (bih0[n]+bhh0[n])
// 128x128 tile, BK=16, 256 threads, 8x8 per thread.
// ---------------------------------------------------------------------------
__global__ __launch_bounds__(256) void k_gemm(const float* __restrict__ A,
                                              const float* __restrict__ B,
                                              const float* __restrict__ bih,
                                              const float* __restrict__ bhh,
                                              float* __restrict__ C) {
    const int K = DM;
    __shared__ float As[16][132];
    __shared__ float Bs[16][132];
    const int tid = threadIdx.x;
    const int m0 = blockIdx.y * 128, n0 = blockIdx.x * 128;
    const int tx = tid & 15, ty = tid >> 4;
    const int lr = tid >> 1;
    const int lc = (tid & 1) * 8;

    float acc[8][8] = {};
    const float4* ag = (const float4*)(A + (size_t)(m0 + lr) * K + lc);
    const float4* bg = (const float4*)(B + (size_t)(n0 + lr) * K + lc);

    for (int k0 = 0; k0 < K; k0 += 16) {
        float4 a0 = ag[0], a1 = ag[1];
        float4 b0 = bg[0], b1v = bg[1];
        ag += 4; bg += 4;
        __syncthreads();
        As[lc + 0][lr] = a0.x; As[lc + 1][lr] = a0.y; As[lc + 2][lr] = a0.z; As[lc + 3][lr] = a0.w;
        As[lc + 4][lr] = a1.x; As[lc + 5][lr] = a1.y; As[lc + 6][lr] = a1.z; As[lc + 7][lr] = a1.w;
        Bs[lc + 0][lr] = b0.x; Bs[lc + 1][lr] = b0.y; Bs[lc + 2][lr] = b0.z; Bs[lc + 3][lr] = b0.w;
        Bs[lc + 4][lr] = b1v.x; Bs[lc + 5][lr] = b1v.y; Bs[lc + 6][lr] = b1v.z; Bs[lc + 7][lr] = b1v.w;
        __syncthreads();
#pragma unroll
        for (int k = 0; k < 16; k++) {
            float a[8], b[8];
            *(float4*)&a[0] = *(const float4*)&As[k][ty * 8 + 0];
            *(float4*)&a[4] = *(const float4*)&As[k][ty * 8 + 4];
            *(float4*)&b[0] = *(const float4*)&Bs[k][tx * 8 + 0];
            *(float4*)&b[4] = *(const float4*)&Bs[k][tx * 8 + 4];
#pragma unroll
            for (int i = 0; i < 8; i++)
#pragma unroll
                for (int j = 0; j < 8; j++)
                    acc[i][j] += a[i] * b[j];
        }
    }
    float bj[8];
#pragma unroll
    for (int j = 0; j < 8; j++) {
        int n = n0 + tx * 8 + j;
        bj[j] = bih[n] + bhh[n];
    }
#pragma unroll
    for (int i = 0; i < 8; i++) {
        float4 v0, v1;
        v0.x = acc[i][0] + bj[0]; v0.y = acc[i][1] + bj[1];
        v0.z = acc[i][2] + bj[2]; v0.w = acc[i][3] + bj[3];
        v1.x = acc[i][4] + bj[4]; v1.y = acc[i][5] + bj[5];
        v1.z = acc[i][6] + bj[6]; v1.w = acc[i][7] + bj[7];
        float* cp = C + (size_t)(m0 + ty * 8 + i) * G4 + n0 + tx * 8;
        *(float4*)(cp + 0) = v0;
        *(float4*)(cp + 4) = v1;
    }
}

// ---------------------------------------------------------------------------
// K2b: sentinel-clear the h0 history region (reuses the dead x buffer).
// ---------------------------------------------------------------------------
__global__ __launch_bounds__(256) void k_clear(u32* __restrict__ p) {
    uint4 v; v.x = SENT; v.y = SENT; v.z = SENT; v.w = SENT;
    ((uint4*)p)[(size_t)blockIdx.x * 256 + threadIdx.x] = v;
}

// ---------------------------------------------------------------------------
// K3: R14 = R13's decoupled layer scans + TIMED waits (no unpaced spins).
//
// Ladder of evidence:
//  R10 (10.77ms): lockstep 2-phase; each poll had ~half-round gap -> first
//    polls hit, 1 burst/round, but 2 serialized RTs + 2 barriers = 6300cy.
//  R11/R12/R13: any poll with ~zero publish->poll gap that spins unpaced
//    storms the MALL (FETCH 1.1-1.4GB, RT inflates 2-4x).
//  R14: decoupled loops (one RT each, concurrent) where every zero-gap wait
//    is paid as SILENT TIME: s_sleep(S_RING)~2048cy, then ONE load burst
//    (memory state sampled at ~2750cy after publish >= RT -> hit), paced
//    retries only as fallback. L1's h0hist reads are load-first (L0 runs
//    ahead structurally -> always hit; retry only during initial catch-up).
// Expected per-round: ~3300-3600cy per loop, concurrent -> scan ~6ms.
// ---------------------------------------------------------------------------
__global__ __launch_bounds__(256, 2) void k_scan2(
        const float* __restrict__ xg,     // T x 4096 layer-0 preacts
        const float* __restrict__ Wih1,
        const float* __restrict__ Whh0,
        const float* __restrict__ Whh1,
        const float* __restrict__ bih1,
        const float* __restrict__ bhh1,
        u32* h0hist,                      // [T][1024] h0 stream (sentinel-init)
        u64* sl1,                         // [2][1024] tagged h1 slots
        float* __restrict__ out) {
    const int tid  = threadIdx.x;
    const bool isL0 = (blockIdx.x < 256);
    const int w    = isL0 ? blockIdx.x : (blockIdx.x - 256);
    const int wv   = tid >> 6;            // wave 0..3 == state index s
    const int ln   = tid & 63;            // lane
    const int rs   = tid >> 4;            // row slot 0..15 (s_i = rs>>2 == wv)
    const int ck   = tid & 15;            // k-chunk of 64
    const int g_i  = rs & 3;              // gate
    const int r    = g_i * DM + w * 4 + wv;   // global gate row

    __shared__ uint4 hstA[2][16][9];      // h0 staged (f16), parity dbuf
    __shared__ uint4 hstB[2][16][9];      // h1 staged (f16), parity dbuf (L1)

    const int stc = tid >> 4;             // stage chunk for h[tid*4..+4)
    const int sto = tid & 15;             // u64 index within chunk row

    if (isL0) {
        // ---------------- Layer-0 producer loop ----------------
        uint4 wr0[8];                     // Whh0 row r as f16 pairs (32 VGPR)
        {
            const float4* gw = (const float4*)(Whh0 + (size_t)r * DM + ck * 64);
#pragma unroll
            for (int e = 0; e < 8; e++) {
                float4 a = gw[2 * e], b = gw[2 * e + 1];
                uint4 q;
                q.x = pk2_(a.x, a.y); q.y = pk2_(a.z, a.w);
                q.z = pk2_(b.x, b.y); q.w = pk2_(b.z, b.w);
                wr0[e] = q;
            }
        }
        float c0 = 0.f, h0v = 0.f;
        float xgv = (ck == 0) ? xg[r] : 0.f;

        for (int t = 0; t < T_SEQ; t++) {
            const int par = t & 1;
            // stage h0(t-1): zero-gap ring -> timed wait, then ONE burst.
            if (t == 0) {
                ((u64*)&hstA[0][stc][0])[sto] = 0ull;
            } else {
                PAUSE(S_RING);            // silent wait ~2048cy (covers RT)
                const u32* hp = h0hist + (size_t)(t - 1) * DM + tid * 4;
                u32 v0, v1, v2, v3;
                for (;;) {
                    v0 = __hip_atomic_load(hp + 0, __ATOMIC_RELAXED, __HIP_MEMORY_SCOPE_AGENT);
                    v1 = __hip_atomic_load(hp + 1, __ATOMIC_RELAXED, __HIP_MEMORY_SCOPE_AGENT);
                    v2 = __hip_atomic_load(hp + 2, __ATOMIC_RELAXED, __HIP_MEMORY_SCOPE_AGENT);
                    v3 = __hip_atomic_load(hp + 3, __ATOMIC_RELAXED, __HIP_MEMORY_SCOPE_AGENT);
                    if ((v0 != SENT) & (v1 != SENT) & (v2 != SENT) & (v3 != SENT)) break;
                    PAUSE(S_RETRY);       // paced fallback, never unpaced
                }
                u32 q0 = pk2_(__uint_as_float(v0), __uint_as_float(v1));
                u32 q1 = pk2_(__uint_as_float(v2), __uint_as_float(v3));
                ((u64*)&hstA[par][stc][0])[sto] = ((u64)q1 << 32) | q0;
            }
            __syncthreads();              // the ONLY barrier per round

            // dot0: Whh0 row r · h0(t-1), weights in VGPRs
            float acc = 0.f;
#pragma unroll
            for (int e = 0; e < 8; e++)
                acc = dot8a_(wr0[e], hstA[par][ck][e], acc);
#pragma unroll
            for (int m = 1; m <= 8; m <<= 1) acc += __shfl_xor(acc, m, 64);
            if (ck == 0) acc += xgv;      // lanes 0,16,32,48 hold gate preacts

            float pi = __shfl(acc, 0, 64);
            float pf = __shfl(acc, 16, 64);
            float pg = __shfl(acc, 32, 64);
            float po = __shfl(acc, 48, 64);
            if (ln == 0) {
                c0 = sigmoidf_(pf) * c0 + sigmoidf_(pi) * tanhf_(pg);
                h0v = sigmoidf_(po) * tanhf_(c0);
                __hip_atomic_store(h0hist + (size_t)t * DM + w * 4 + wv,
                                   __float_as_uint(h0v),
                                   __ATOMIC_RELAXED, __HIP_MEMORY_SCOPE_AGENT);
            }
            // xg prefetch for t+1 (off the critical chain)
            float xgn = 0.f;
            if (ck == 0 && t + 1 < T_SEQ) xgn = xg[(size_t)(t + 1) * G4 + r];
            xgv = xgn;
        }
        // L0 WGs exit; h0hist persists for L1 consumers.
    } else {
        // ---------------- Layer-1 consumer loop ----------------
        uint4 wi1[8], wh1[8];             // Wih1/Whh1 rows (64 VGPR)
        {
            const float4* ga = (const float4*)(Wih1 + (size_t)r * DM + ck * 64);
            const float4* gb = (const float4*)(Whh1 + (size_t)r * DM + ck * 64);
#pragma unroll
            for (int e = 0; e < 8; e++) {
                float4 a = ga[2 * e], b = ga[2 * e + 1];
                uint4 q;
                q.x = pk2_(a.x, a.y); q.y = pk2_(a.z, a.w);
                q.z = pk2_(b.x, b.y); q.w = pk2_(b.z, b.w);
                wi1[e] = q;
                a = gb[2 * e]; b = gb[2 * e + 1];
                q.x = pk2_(a.x, a.y); q.y = pk2_(a.z, a.w);
                q.z = pk2_(b.x, b.y); q.w = pk2_(b.z, b.w);
                wh1[e] = q;
            }
        }
        float b1s[4] = {0.f, 0.f, 0.f, 0.f};
        if (ln == 0) {
#pragma unroll
            for (int gg = 0; gg < 4; gg++)
                b1s[gg] = bih1[gg * DM + w * 4 + wv] + bhh1[gg * DM + w * 4 + wv];
        }
        float c1 = 0.f, h1v = 0.f;

        for (int t = 0; t < T_SEQ; t++) {
            const int par = t & 1;
            const u32* hp = h0hist + (size_t)t * DM + tid * 4;

            // (a) issue h0hist loads FIRST (L0 leads -> expected hit);
            //     their RT hides under the ring sleep below.
            u32 v0 = __hip_atomic_load(hp + 0, __ATOMIC_RELAXED, __HIP_MEMORY_SCOPE_AGENT);
            u32 v1 = __hip_atomic_load(hp + 1, __ATOMIC_RELAXED, __HIP_MEMORY_SCOPE_AGENT);
            u32 v2 = __hip_atomic_load(hp + 2, __ATOMIC_RELAXED, __HIP_MEMORY_SCOPE_AGENT);
            u32 v3 = __hip_atomic_load(hp + 3, __ATOMIC_RELAXED, __HIP_MEMORY_SCOPE_AGENT);

            // (b) silent wait for the zero-gap h1 ring (covers its RT)
            if (t > 0) PAUSE(S_RING);

            // (c) check/stage h0(t); paced catch-up only if L0 is behind
            while ((v0 == SENT) | (v1 == SENT) | (v2 == SENT) | (v3 == SENT)) {
                PAUSE(S_HIST);
                v0 = __hip_atomic_load(hp + 0, __ATOMIC_RELAXED, __HIP_MEMORY_SCOPE_AGENT);
                v1 = __hip_atomic_load(hp + 1, __ATOMIC_RELAXED, __HIP_MEMORY_SCOPE_AGENT);
                v2 = __hip_atomic_load(hp + 2, __ATOMIC_RELAXED, __HIP_MEMORY_SCOPE_AGENT);
                v3 = __hip_atomic_load(hp + 3, __ATOMIC_RELAXED, __HIP_MEMORY_SCOPE_AGENT);
            }
            {
                u32 q0 = pk2_(__uint_as_float(v0), __uint_as_float(v1));
                u32 q1 = pk2_(__uint_as_float(v2), __uint_as_float(v3));
                ((u64*)&hstA[par][stc][0])[sto] = ((u64)q1 << 32) | q0;
            }

            // (d) stage h1(t-1) from the tagged ring: ONE burst post-sleep,
            //     paced retries as fallback.
            if (t == 0) {
                ((u64*)&hstB[0][stc][0])[sto] = 0ull;
            } else {
                const u64* p1 = sl1 + (size_t)par * 1024 + tid * 4;
                const u32 want = (u32)t;
                u64 d0, d1, d2, d3;
                for (;;) {
                    d0 = __hip_atomic_load(p1 + 0, __ATOMIC_RELAXED, __HIP_MEMORY_SCOPE_AGENT);
                    d1 = __hip_atomic_load(p1 + 1, __ATOMIC_RELAXED, __HIP_MEMORY_SCOPE_AGENT);
                    d2 = __hip_atomic_load(p1 + 2, __ATOMIC_RELAXED, __HIP_MEMORY_SCOPE_AGENT);
                    d3 = __hip_atomic_load(p1 + 3, __ATOMIC_RELAXED, __HIP_MEMORY_SCOPE_AGENT);
                    bool ok = ((u32)(d0 >> 32) == want) & ((u32)(d1 >> 32) == want) &
                              ((u32)(d2 >> 32) == want) & ((u32)(d3 >> 32) == want);
                    if (ok) break;
                    PAUSE(S_RETRY);
                }
                u32 q0 = pk2_(__uint_as_float((u32)d0), __uint_as_float((u32)d1));
                u32 q1 = pk2_(__uint_as_float((u32)d2), __uint_as_float((u32)d3));
                ((u64*)&hstB[par][stc][0])[sto] = ((u64)q1 << 32) | q0;
            }
            __syncthreads();              // the ONLY barrier per round

            // dot1: Wih1·h0(t); dot2: Whh1·h1(t-1) — both weights in VGPRs
            float a1 = 0.f, a2 = 0.f;
#pragma unroll
            for (int e = 0; e < 8; e++) {
                a1 = dot8a_(wi1[e], hstA[par][ck][e], a1);
                a2 = dot8a_(wh1[e], hstB[par][ck][e], a2);
            }
#pragma unroll
            for (int m = 1; m <= 8; m <<= 1) {
                a1 += __shfl_xor(a1, m, 64);
                a2 += __shfl_xor(a2, m, 64);
            }
            float pi = __shfl(a1, 0, 64)  + __shfl(a2, 0, 64);
            float pf = __shfl(a1, 16, 64) + __shfl(a2, 16, 64);
            float pg = __shfl(a1, 32, 64) + __shfl(a2, 32, 64);
            float po = __shfl(a1, 48, 64) + __shfl(a2, 48, 64);
            if (ln == 0) {
                pi += b1s[0]; pf += b1s[1]; pg += b1s[2]; po += b1s[3];
                c1 = sigmoidf_(pf) * c1 + sigmoidf_(pi) * tanhf_(pg);
                h1v = sigmoidf_(po) * tanhf_(c1);
                u64 v = ((u64)(u32)(t + 1) << 32) | (u64)__float_as_uint(h1v);
                __hip_atomic_store(sl1 + (size_t)((t + 1) & 1) * 1024 + w * 4 + wv,
                                   v, __ATOMIC_RELAXED, __HIP_MEMORY_SCOPE_AGENT);
            }
            // Hazards (single barrier): hstA/hstB[par] written pre-B(t),
            // read post-B(t); next write to same parity is pre-B(t+2), i.e.
            // after B(t+1) -> ordered after all round-t reads. Ring tag
            // staleness: cross-run finals are 4095/4096, never equal to the
            // wanted small tags before first overwrite (R10 argument).
        }
        if (ln == 0) out[w * 4 + wv] = lrelu_(h1v);   // h1[T-1]
    }
}

// ---------------------------------------------------------------------------
extern "C" void kernel_launch(void* const* d_in, const int* in_sizes, int n_in,
                              void* d_out, int out_size, void* d_ws, size_t ws_size,
                              hipStream_t stream) {
    const float* inp = (const float*)d_in[0];   // 4096 x 64
    const float* W1  = (const float*)d_in[1];   // 1024 x 64
    const float* b1  = (const float*)d_in[2];   // 1024
    const float* Wih = (const float*)d_in[3];   // 2 x 4096 x 1024
    const float* Whh = (const float*)d_in[4];   // 2 x 4096 x 1024
    const float* bih = (const float*)d_in[5];   // 2 x 4096
    const float* bhh = (const float*)d_in[6];   // 2 x 4096
    float* out = (float*)d_out;                 // 1024

    // workspace layout:
    //   x: 4096*1024 f32 (K1 out, K2 in) -> REUSED as h0hist (16 MB) after K2
    //   xg: 4096*4096 f32
    //   sl1: 2*1024 u64
    float* x   = (float*)d_ws;
    float* xg  = x + (size_t)T_SEQ * DM;
    u64*   sl1 = (u64*)(xg + (size_t)T_SEQ * G4);
    u32*   h0hist = (u32*)x;
    (void)in_sizes; (void)n_in; (void)out_size; (void)ws_size;

    // Phase 1: input projection
    k_input<<<dim3(T_SEQ), dim3(256), 0, stream>>>(inp, W1, b1, x);

    // Phase 2: xg = x @ Wih0^T + (bih0+bhh0)
    k_gemm<<<dim3(32, 32), dim3(256), 0, stream>>>(x, Wih, bih, bhh, xg);

    // Phase 2b: x is now dead -> sentinel-clear it as the h0 history
    k_clear<<<dim3(4096), dim3(256), 0, stream>>>(h0hist);

    // Phase 3: decoupled layer scans with timed waits (256 L0 + 256 L1 WGs)
    k_scan2<<<dim3(512), dim3(256), 0, stream>>>(
        xg, Wih + LSTRIDE_W, Whh, Whh + LSTRIDE_W,
        bih + LSTRIDE_B, bhh + LSTRIDE_B, h0hist, sl1, out);
}